// Round 2
// baseline (324.895 us; speedup 1.0000x reference)
//
#include <hip/hip_runtime.h>
#include <math.h>

#define Bz 64
#define Sz 512
#define Hz 768
#define Nz 128
#define Ez 1024
#define GHz 128
#define FHz 256
#define Lz 2
#define BNz (Bz * Nz)          // 8192

typedef short bf16x8 __attribute__((ext_vector_type(8)));
typedef float f32x4  __attribute__((ext_vector_type(4)));
typedef unsigned short ushort;

__device__ inline ushort f2b(float f) {          // f32 -> bf16 bits, round-to-nearest-even
    union { float f; unsigned u; } v; v.f = f;
    return (ushort)((v.u + 0x7FFFu + ((v.u >> 16) & 1u)) >> 16);
}

// ============ prep: W1,W2 -> TRANSPOSED bf16 [n][k] (blocks 0..447) + per-batch CSR (blocks 448..511) ============
__global__ void k_prep(const float* __restrict__ W1, const float* __restrict__ W2,
                       const int* __restrict__ ei,
                       ushort* __restrict__ W1T, ushort* __restrict__ W2T,
                       int* __restrict__ rowptrG, int* __restrict__ srcsG,
                       float* __restrict__ wnG, float* __restrict__ dinvG) {
    int blk = blockIdx.x, t = threadIdx.x;       // 256 threads
    if (blk < 448) {                             // weight conversion + transpose
        int i = blk * 256 + t;
        if (i < Hz * GHz) { int k = i >> 7, n = i & 127; W1T[n * Hz + k] = f2b(W1[i]); }
        int j = i - Hz * GHz;
        if (j >= 0 && j < GHz * GHz) { int k = j >> 7, n = j & 127; W2T[n * GHz + k] = f2b(W2[j]); }
        return;
    }
    int b = blk - 448;
    __shared__ int srcl[Ez], dstl[Ez];
    __shared__ int hist[Nz], off[Nz], rp[Nz + 1];
    __shared__ float di[Nz];
    if (t < Nz) { hist[t] = 0; off[t] = 0; }
    __syncthreads();
    #pragma unroll
    for (int j = 0; j < 4; ++j) {
        int e = t + 256 * j;
        int s = ei[b * 2 * Ez + e], d = ei[b * 2 * Ez + Ez + e];
        srcl[e] = s; dstl[e] = d;
        atomicAdd(&hist[d], 1);
    }
    __syncthreads();
    if (t < Nz) {
        di[t] = rsqrtf((float)hist[t] + 1.0f);
        dinvG[b * Nz + t] = di[t];
    }
    __syncthreads();
    if (t == 0) {
        int run = 0;
        for (int n = 0; n < Nz; ++n) { rp[n] = run; run += hist[n]; }
        rp[Nz] = run;
    }
    __syncthreads();
    #pragma unroll
    for (int j = 0; j < 4; ++j) {
        int e = t + 256 * j;
        int s = srcl[e], d = dstl[e];
        int pos = rp[d] + atomicAdd(&off[d], 1);
        srcsG[b * Ez + pos] = s;
        wnG[b * Ez + pos] = di[s] * di[d];
    }
    if (t < Nz + 1) rowptrG[b * (Nz + 1) + t] = rp[t];
}

// ============ node gather: per (b,n) block; wave-synchronous gate; writes nf in bf16 ============
__global__ void k_node_gather(const float* __restrict__ lh, const int* __restrict__ submap,
                              const float* __restrict__ wr, const float* __restrict__ br,
                              ushort* __restrict__ nfb) {
    int n = blockIdx.x, b = blockIdx.y;
    int t = threadIdx.x;                  // 128 = 2 waves
    int lane = t & 63, wid = t >> 6;
    __shared__ int list[Sz];
    __shared__ int lcnt;
    __shared__ float partial[Hz];
    if (t == 0) lcnt = 0;
    __syncthreads();
    #pragma unroll
    for (int j = 0; j < 4; ++j) {
        int s = t + 128 * j;
        if (submap[b * Sz + s] == n) { int p = atomicAdd(&lcnt, 1); list[p] = s; }
    }
    __syncthreads();
    int cnt = lcnt;
    float brv = br[0];
    const float* wp = wr + lane * 12;
    float4 w0 = *(const float4*)&wp[0];
    float4 w1 = *(const float4*)&wp[4];
    float4 w2 = *(const float4*)&wp[8];
    float4 a0 = {0,0,0,0}, a1 = {0,0,0,0}, a2 = {0,0,0,0};
    for (int i = wid; i < cnt; i += 2) {
        const float* x = lh + (size_t)(b * Sz + list[i]) * Hz + lane * 12;
        float4 v0 = *(const float4*)&x[0];
        float4 v1 = *(const float4*)&x[4];
        float4 v2 = *(const float4*)&x[8];
        float p = v0.x*w0.x + v0.y*w0.y + v0.z*w0.z + v0.w*w0.w
                + v1.x*w1.x + v1.y*w1.y + v1.z*w1.z + v1.w*w1.w
                + v2.x*w2.x + v2.y*w2.y + v2.z*w2.z + v2.w*w2.w;
        #pragma unroll
        for (int off = 32; off > 0; off >>= 1) p += __shfl_down(p, off);
        float z = __shfl(p, 0) + brv;
        float g = 1.0f / (1.0f + __expf(-z));
        a0.x += g*v0.x; a0.y += g*v0.y; a0.z += g*v0.z; a0.w += g*v0.w;
        a1.x += g*v1.x; a1.y += g*v1.y; a1.z += g*v1.z; a1.w += g*v1.w;
        a2.x += g*v2.x; a2.y += g*v2.y; a2.z += g*v2.z; a2.w += g*v2.w;
    }
    if (wid == 1) {
        float* pp = partial + lane * 12;
        *(float4*)&pp[0] = a0; *(float4*)&pp[4] = a1; *(float4*)&pp[8] = a2;
    }
    __syncthreads();
    if (wid == 0) {
        float invc = 1.0f / fmaxf((float)cnt, 1.0f);
        const float* pp = partial + lane * 12;
        float4 p0 = *(const float4*)&pp[0];
        float4 p1 = *(const float4*)&pp[4];
        float4 p2 = *(const float4*)&pp[8];
        float o[12];
        o[0]=(a0.x+p0.x)*invc; o[1]=(a0.y+p0.y)*invc; o[2]=(a0.z+p0.z)*invc; o[3]=(a0.w+p0.w)*invc;
        o[4]=(a1.x+p1.x)*invc; o[5]=(a1.y+p1.y)*invc; o[6]=(a1.z+p1.z)*invc; o[7]=(a1.w+p1.w)*invc;
        o[8]=(a2.x+p2.x)*invc; o[9]=(a2.y+p2.y)*invc; o[10]=(a2.z+p2.z)*invc; o[11]=(a2.w+p2.w)*invc;
        unsigned* ob = (unsigned*)(nfb + (size_t)(b * Nz + n) * Hz + lane * 12);
        #pragma unroll
        for (int j = 0; j < 6; ++j)
            ob[j] = (unsigned)f2b(o[2*j]) | ((unsigned)f2b(o[2*j+1]) << 16);
    }
}

// ============ fused per-batch GNN: GEMM1 + edge1 + GEMM2 + edge2 + mean-pool, all in LDS ============
// Block = 1 batch, 512 threads = 8 waves (2 M x 4 N). Edges never cross batches, so the whole
// 2-layer GCN for batch b lives in LDS (~152KB). Only output: pooled[b][128].
// MFMA layouts per m89/m91: A[m=lane&15][k=q*8+j]; B[k][n=lane&15]; C row=q*4+r, col=lane&15.
// ALL LDS row strides must keep ds_read_b128 16B-aligned: GSP=72 (144B=9x16),
// HP=132 (528B=33x16, scalar-only anyway), XP=136 (272B=17x16 -- 132 was the R1 fault: 264B).
#define GSP 72                  // staging row stride in bf16
#define HP  132                 // h row stride in f32
#define XP  136                 // x1 row stride in bf16 (16B-aligned rows for b128 reads)
__global__ __launch_bounds__(512) void k_gnn_fused(
        const ushort* __restrict__ nfb, const ushort* __restrict__ W1T,
        const ushort* __restrict__ W2T,
        const int* __restrict__ rowptrG, const int* __restrict__ srcsG,
        const float* __restrict__ wnG, const float* __restrict__ dinvG,
        const float* __restrict__ b1, const float* __restrict__ b2,
        float* __restrict__ pooledG) {
    __shared__ __align__(16) ushort As[128 * GSP];   // 18.4KB  A-staging [row][k64]
    __shared__ __align__(16) ushort Bs[128 * GSP];   // 18.4KB  B-staging [n][k64]
    __shared__ __align__(16) float  hL[128 * HP];    // 67.6KB  GEMM out (pre-aggregation), f32
    __shared__ __align__(16) ushort xb[128 * XP];    // 34.8KB  x1 bf16 [d][k]
    __shared__ int   rp[Nz + 1];
    __shared__ int   srcl[Ez];
    __shared__ float wnl[Ez];
    __shared__ float dil[Nz];
    __shared__ float wsum[8 * 128];

    int b = blockIdx.x;
    int t = threadIdx.x;
    int w = t >> 6, lane = t & 63;
    int q = lane >> 4, l16 = lane & 15;
    int wm = w >> 2, wn2 = w & 3;                    // wave tile: rows wm*64+, cols wn2*32+

    // ---- CSR -> LDS ----
    if (t < Nz + 1) rp[t] = rowptrG[b * (Nz + 1) + t];
    if (t < Nz) dil[t] = dinvG[b * Nz + t];
    #pragma unroll
    for (int j = 0; j < 2; ++j) {
        int e = t + 512 * j;
        srcl[e] = srcsG[b * Ez + e];
        wnl[e]  = wnG[b * Ez + e];
    }

    // staging decomposition: 1024 uint4 chunks (128 rows x 8 k-segs), 2 per thread
    int r0 = t >> 3, s0 = t & 7;                     // r0 in 0..63
    int r1 = r0 + 64;

    f32x4 acc[4][2];
    #pragma unroll
    for (int mf = 0; mf < 4; ++mf)
        #pragma unroll
        for (int nf = 0; nf < 2; ++nf) acc[mf][nf] = (f32x4){0, 0, 0, 0};

    // ---- GEMM1: hL = nf(128x768) @ W1(768x128), reg-prefetched 64-k steps ----
    const ushort* Ab = nfb + (size_t)b * Nz * Hz;
    uint4 apre[2], bpre[2];
    auto loadT1 = [&](int k0) {
        apre[0] = *(const uint4*)&Ab[(size_t)r0 * Hz + k0 + s0 * 8];
        apre[1] = *(const uint4*)&Ab[(size_t)r1 * Hz + k0 + s0 * 8];
        bpre[0] = *(const uint4*)&W1T[(size_t)r0 * Hz + k0 + s0 * 8];
        bpre[1] = *(const uint4*)&W1T[(size_t)r1 * Hz + k0 + s0 * 8];
    };
    loadT1(0);
    for (int k0 = 0; k0 < Hz; k0 += 64) {
        __syncthreads();
        *(uint4*)&As[r0 * GSP + s0 * 8] = apre[0];
        *(uint4*)&As[r1 * GSP + s0 * 8] = apre[1];
        *(uint4*)&Bs[r0 * GSP + s0 * 8] = bpre[0];
        *(uint4*)&Bs[r1 * GSP + s0 * 8] = bpre[1];
        if (k0 + 64 < Hz) loadT1(k0 + 64);
        __syncthreads();
        #pragma unroll
        for (int ks = 0; ks < 64; ks += 32)
            #pragma unroll
            for (int mf = 0; mf < 4; ++mf) {
                bf16x8 af = *(const bf16x8*)&As[(wm * 64 + mf * 16 + l16) * GSP + ks + q * 8];
                #pragma unroll
                for (int nf = 0; nf < 2; ++nf) {
                    bf16x8 bv = *(const bf16x8*)&Bs[(wn2 * 32 + nf * 16 + l16) * GSP + ks + q * 8];
                    acc[mf][nf] = __builtin_amdgcn_mfma_f32_16x16x32_bf16(af, bv, acc[mf][nf], 0, 0, 0);
                }
            }
    }
    #pragma unroll
    for (int mf = 0; mf < 4; ++mf)
        #pragma unroll
        for (int nf = 0; nf < 2; ++nf)
            #pragma unroll
            for (int r = 0; r < 4; ++r)
                hL[(wm * 64 + mf * 16 + q * 4 + r) * HP + wn2 * 32 + nf * 16 + l16] = acc[mf][nf][r];
    __syncthreads();

    // ---- edge1: x1 = relu(agg(hL) + b1) -> xb bf16 ----
    float b1v0 = b1[lane], b1v1 = b1[lane + 64];
    for (int d = w; d < Nz; d += 8) {
        float dd = dil[d];
        float a0 = hL[d * HP + lane] * dd * dd;
        float a1 = hL[d * HP + lane + 64] * dd * dd;
        int pe = rp[d + 1];
        for (int i = rp[d]; i < pe; ++i) {
            int s = srcl[i]; float nm = wnl[i];
            a0 += hL[s * HP + lane] * nm;
            a1 += hL[s * HP + lane + 64] * nm;
        }
        xb[d * XP + lane]      = f2b(fmaxf(a0 + b1v0, 0.0f));
        xb[d * XP + lane + 64] = f2b(fmaxf(a1 + b1v1, 0.0f));
    }
    __syncthreads();

    // ---- GEMM2: hL = x1(128x128, LDS) @ W2(128x128) ----
    #pragma unroll
    for (int mf = 0; mf < 4; ++mf)
        #pragma unroll
        for (int nf = 0; nf < 2; ++nf) acc[mf][nf] = (f32x4){0, 0, 0, 0};
    for (int k0 = 0; k0 < GHz; k0 += 64) {
        __syncthreads();
        *(uint4*)&Bs[r0 * GSP + s0 * 8] = *(const uint4*)&W2T[(size_t)r0 * GHz + k0 + s0 * 8];
        *(uint4*)&Bs[r1 * GSP + s0 * 8] = *(const uint4*)&W2T[(size_t)r1 * GHz + k0 + s0 * 8];
        __syncthreads();
        #pragma unroll
        for (int ks = 0; ks < 64; ks += 32)
            #pragma unroll
            for (int mf = 0; mf < 4; ++mf) {
                bf16x8 af = *(const bf16x8*)&xb[(wm * 64 + mf * 16 + l16) * XP + k0 + ks + q * 8];
                #pragma unroll
                for (int nf = 0; nf < 2; ++nf) {
                    bf16x8 bv = *(const bf16x8*)&Bs[(wn2 * 32 + nf * 16 + l16) * GSP + ks + q * 8];
                    acc[mf][nf] = __builtin_amdgcn_mfma_f32_16x16x32_bf16(af, bv, acc[mf][nf], 0, 0, 0);
                }
            }
    }
    #pragma unroll
    for (int mf = 0; mf < 4; ++mf)
        #pragma unroll
        for (int nf = 0; nf < 2; ++nf)
            #pragma unroll
            for (int r = 0; r < 4; ++r)
                hL[(wm * 64 + mf * 16 + q * 4 + r) * HP + wn2 * 32 + nf * 16 + l16] = acc[mf][nf][r];
    __syncthreads();

    // ---- edge2 + mean-pool (x2 never materialized) ----
    float b2v0 = b2[lane], b2v1 = b2[lane + 64];
    float p0 = 0.0f, p1 = 0.0f;
    for (int d = w; d < Nz; d += 8) {
        float dd = dil[d];
        float a0 = hL[d * HP + lane] * dd * dd;
        float a1 = hL[d * HP + lane + 64] * dd * dd;
        int pe = rp[d + 1];
        for (int i = rp[d]; i < pe; ++i) {
            int s = srcl[i]; float nm = wnl[i];
            a0 += hL[s * HP + lane] * nm;
            a1 += hL[s * HP + lane + 64] * nm;
        }
        p0 += fmaxf(a0 + b2v0, 0.0f);
        p1 += fmaxf(a1 + b2v1, 0.0f);
    }
    wsum[w * 128 + lane]      = p0;
    wsum[w * 128 + lane + 64] = p1;
    __syncthreads();
    if (t < Nz) {
        float s = 0.0f;
        #pragma unroll
        for (int ww = 0; ww < 8; ++ww) s += wsum[ww * 128 + t];
        pooledG[b * Nz + t] = s * (1.0f / Nz);
    }
}

// ============ fused head: h = relu([cls,pooled]@Wf1+bf1); out = h@Wf2+bf2 ============
__global__ void k_head(const float* __restrict__ lh, const float* __restrict__ pooled,
                       const float* __restrict__ Wf1, const float* __restrict__ bf1,
                       const float* __restrict__ Wf2, const float* __restrict__ bf2,
                       float* __restrict__ out) {
    int b = blockIdx.x;
    int t = threadIdx.x;                  // 256
    __shared__ float in[Hz + GHz];        // 896
    __shared__ float4 red4[4][64];
    __shared__ float hvec[FHz];
    __shared__ float red[256];
    for (int i = t; i < Hz; i += 256) in[i] = lh[(size_t)b * Sz * Hz + i];   // cls = s=0 row
    if (t < GHz) in[Hz + t] = pooled[b * GHz + t];
    __syncthreads();
    int c4 = t & 63, kc = t >> 6;
    float4 a = {0, 0, 0, 0};
    int k1 = kc * 224 + 224;
    for (int k = kc * 224; k < k1; ++k) {
        float iv = in[k];
        float4 w = *(const float4*)&Wf1[(size_t)k * FHz + c4 * 4];
        a.x += iv * w.x; a.y += iv * w.y; a.z += iv * w.z; a.w += iv * w.w;
    }
    red4[kc][c4] = a;
    __syncthreads();
    if (t < 64) {
        float4 s0 = red4[0][t], s1 = red4[1][t], s2 = red4[2][t], s3 = red4[3][t];
        float4 bb = *(const float4*)&bf1[t * 4];
        hvec[t * 4 + 0] = fmaxf(s0.x + s1.x + s2.x + s3.x + bb.x, 0.0f);
        hvec[t * 4 + 1] = fmaxf(s0.y + s1.y + s2.y + s3.y + bb.y, 0.0f);
        hvec[t * 4 + 2] = fmaxf(s0.z + s1.z + s2.z + s3.z + bb.z, 0.0f);
        hvec[t * 4 + 3] = fmaxf(s0.w + s1.w + s2.w + s3.w + bb.w, 0.0f);
    }
    __syncthreads();
    float hv = hvec[t];
    for (int l = 0; l < Lz; ++l) {
        red[t] = hv * Wf2[t * Lz + l];
        __syncthreads();
        for (int s2 = 128; s2 > 0; s2 >>= 1) {
            if (t < s2) red[t] += red[t + s2];
            __syncthreads();
        }
        if (t == 0) out[b * Lz + l] = red[0] + bf2[l];
        __syncthreads();
    }
}

extern "C" void kernel_launch(void* const* d_in, const int* in_sizes, int n_in,
                              void* d_out, int out_size, void* d_ws, size_t ws_size,
                              hipStream_t stream) {
    const float* lh     = (const float*)d_in[0];
    const int*   submap = (const int*)d_in[1];
    const int*   ei     = (const int*)d_in[2];
    const float* wr  = (const float*)d_in[4];
    const float* br  = (const float*)d_in[5];
    const float* W1  = (const float*)d_in[6];
    const float* b1  = (const float*)d_in[7];
    const float* W2  = (const float*)d_in[8];
    const float* b2  = (const float*)d_in[9];
    const float* Wf1 = (const float*)d_in[10];
    const float* bf1 = (const float*)d_in[11];
    const float* Wf2 = (const float*)d_in[12];
    const float* bf2 = (const float*)d_in[13];
    float* out = (float*)d_out;

    // ---- workspace layout (16B-aligned chunks) ----
    char* p = (char*)d_ws;
    ushort* nfb  = (ushort*)p;  p += (size_t)BNz * Hz * 2;      // 12.6 MB bf16
    ushort* W1T  = (ushort*)p;  p += (size_t)Hz * GHz * 2;      // transposed [n][k]
    ushort* W2T  = (ushort*)p;  p += (size_t)GHz * GHz * 2;     // transposed [n][k]
    int*    rowptrG = (int*)p;  p += (size_t)Bz * (Nz + 1) * 4;
    int*    srcsG   = (int*)p;  p += (size_t)Bz * Ez * 4;
    float*  wnG     = (float*)p; p += (size_t)Bz * Ez * 4;
    float*  dinvG   = (float*)p; p += (size_t)Bz * Nz * 4;
    float*  pooledG = (float*)p; p += (size_t)Bz * GHz * 4;

    // 4 dispatches; no memsets, no global atomics; GNN intermediates never leave LDS
    k_prep<<<512, 256, 0, stream>>>(W1, W2, ei, W1T, W2T, rowptrG, srcsG, wnG, dinvG);
    k_node_gather<<<dim3(Nz, Bz), 128, 0, stream>>>(lh, submap, wr, br, nfb);
    k_gnn_fused<<<Bz, 512, 0, stream>>>(nfb, W1T, W2T, rowptrG, srcsG, wnG, dinvG,
                                        b1, b2, pooledG);
    k_head<<<Bz, 256, 0, stream>>>(lh, pooledG, Wf1, bf1, Wf2, bf2, out);
}

// Round 3
// 248.017 us; speedup vs baseline: 1.3100x; 1.3100x over previous
//
#include <hip/hip_runtime.h>
#include <math.h>

#define Bz 64
#define Sz 512
#define Hz 768
#define Nz 128
#define Ez 1024
#define GHz 128
#define FHz 256
#define Lz 2
#define BNz (Bz * Nz)          // 8192

typedef short bf16x8 __attribute__((ext_vector_type(8)));
typedef float f32x4  __attribute__((ext_vector_type(4)));
typedef unsigned short ushort;

__device__ inline ushort f2b(float f) {          // f32 -> bf16 bits, round-to-nearest-even
    union { float f; unsigned u; } v; v.f = f;
    return (ushort)((v.u + 0x7FFFu + ((v.u >> 16) & 1u)) >> 16);
}

// ============ prep: W1,W2 -> TRANSPOSED bf16 [n][k] (blocks 0..447) + per-batch CSR (blocks 448..511) ============
__global__ void k_prep(const float* __restrict__ W1, const float* __restrict__ W2,
                       const int* __restrict__ ei,
                       ushort* __restrict__ W1T, ushort* __restrict__ W2T,
                       int* __restrict__ rowptrG, int* __restrict__ srcsG,
                       float* __restrict__ wnG, float* __restrict__ dinvG) {
    int blk = blockIdx.x, t = threadIdx.x;       // 256 threads
    if (blk < 448) {                             // weight conversion + transpose
        int i = blk * 256 + t;
        if (i < Hz * GHz) { int k = i >> 7, n = i & 127; W1T[n * Hz + k] = f2b(W1[i]); }
        int j = i - Hz * GHz;
        if (j >= 0 && j < GHz * GHz) { int k = j >> 7, n = j & 127; W2T[n * GHz + k] = f2b(W2[j]); }
        return;
    }
    int b = blk - 448;
    __shared__ int srcl[Ez], dstl[Ez];
    __shared__ int hist[Nz], off[Nz], rp[Nz + 1];
    __shared__ float di[Nz];
    if (t < Nz) { hist[t] = 0; off[t] = 0; }
    __syncthreads();
    #pragma unroll
    for (int j = 0; j < 4; ++j) {
        int e = t + 256 * j;
        int s = ei[b * 2 * Ez + e], d = ei[b * 2 * Ez + Ez + e];
        srcl[e] = s; dstl[e] = d;
        atomicAdd(&hist[d], 1);
    }
    __syncthreads();
    if (t < Nz) {
        di[t] = rsqrtf((float)hist[t] + 1.0f);
        dinvG[b * Nz + t] = di[t];
    }
    __syncthreads();
    if (t == 0) {
        int run = 0;
        for (int n = 0; n < Nz; ++n) { rp[n] = run; run += hist[n]; }
        rp[Nz] = run;
    }
    __syncthreads();
    #pragma unroll
    for (int j = 0; j < 4; ++j) {
        int e = t + 256 * j;
        int s = srcl[e], d = dstl[e];
        int pos = rp[d] + atomicAdd(&off[d], 1);
        srcsG[b * Ez + pos] = s;
        wnG[b * Ez + pos] = di[s] * di[d];
    }
    if (t < Nz + 1) rowptrG[b * (Nz + 1) + t] = rp[t];
}

// ============ node gather: per (b,n) block; wave-synchronous gate; writes nf in bf16 ============
__global__ void k_node_gather(const float* __restrict__ lh, const int* __restrict__ submap,
                              const float* __restrict__ wr, const float* __restrict__ br,
                              ushort* __restrict__ nfb) {
    int n = blockIdx.x, b = blockIdx.y;
    int t = threadIdx.x;                  // 128 = 2 waves
    int lane = t & 63, wid = t >> 6;
    __shared__ int list[Sz];
    __shared__ int lcnt;
    __shared__ float partial[Hz];
    if (t == 0) lcnt = 0;
    __syncthreads();
    #pragma unroll
    for (int j = 0; j < 4; ++j) {
        int s = t + 128 * j;
        if (submap[b * Sz + s] == n) { int p = atomicAdd(&lcnt, 1); list[p] = s; }
    }
    __syncthreads();
    int cnt = lcnt;
    float brv = br[0];
    const float* wp = wr + lane * 12;
    float4 w0 = *(const float4*)&wp[0];
    float4 w1 = *(const float4*)&wp[4];
    float4 w2 = *(const float4*)&wp[8];
    float4 a0 = {0,0,0,0}, a1 = {0,0,0,0}, a2 = {0,0,0,0};
    for (int i = wid; i < cnt; i += 2) {
        const float* x = lh + (size_t)(b * Sz + list[i]) * Hz + lane * 12;
        float4 v0 = *(const float4*)&x[0];
        float4 v1 = *(const float4*)&x[4];
        float4 v2 = *(const float4*)&x[8];
        float p = v0.x*w0.x + v0.y*w0.y + v0.z*w0.z + v0.w*w0.w
                + v1.x*w1.x + v1.y*w1.y + v1.z*w1.z + v1.w*w1.w
                + v2.x*w2.x + v2.y*w2.y + v2.z*w2.z + v2.w*w2.w;
        #pragma unroll
        for (int off = 32; off > 0; off >>= 1) p += __shfl_down(p, off);
        float z = __shfl(p, 0) + brv;
        float g = 1.0f / (1.0f + __expf(-z));
        a0.x += g*v0.x; a0.y += g*v0.y; a0.z += g*v0.z; a0.w += g*v0.w;
        a1.x += g*v1.x; a1.y += g*v1.y; a1.z += g*v1.z; a1.w += g*v1.w;
        a2.x += g*v2.x; a2.y += g*v2.y; a2.z += g*v2.z; a2.w += g*v2.w;
    }
    if (wid == 1) {
        float* pp = partial + lane * 12;
        *(float4*)&pp[0] = a0; *(float4*)&pp[4] = a1; *(float4*)&pp[8] = a2;
    }
    __syncthreads();
    if (wid == 0) {
        float invc = 1.0f / fmaxf((float)cnt, 1.0f);
        const float* pp = partial + lane * 12;
        float4 p0 = *(const float4*)&pp[0];
        float4 p1 = *(const float4*)&pp[4];
        float4 p2 = *(const float4*)&pp[8];
        float o[12];
        o[0]=(a0.x+p0.x)*invc; o[1]=(a0.y+p0.y)*invc; o[2]=(a0.z+p0.z)*invc; o[3]=(a0.w+p0.w)*invc;
        o[4]=(a1.x+p1.x)*invc; o[5]=(a1.y+p1.y)*invc; o[6]=(a1.z+p1.z)*invc; o[7]=(a1.w+p1.w)*invc;
        o[8]=(a2.x+p2.x)*invc; o[9]=(a2.y+p2.y)*invc; o[10]=(a2.z+p2.z)*invc; o[11]=(a2.w+p2.w)*invc;
        unsigned* ob = (unsigned*)(nfb + (size_t)(b * Nz + n) * Hz + lane * 12);
        #pragma unroll
        for (int j = 0; j < 6; ++j)
            ob[j] = (unsigned)f2b(o[2*j]) | ((unsigned)f2b(o[2*j+1]) << 16);
    }
}

// ============ fused per-batch GNN + HEAD: GEMM1+edge1+GEMM2+edge2+pool+head, all in LDS ============
// Block = 1 batch, 512 threads = 8 waves (2 M x 4 N). Output: out[b][2] directly.
// Head folded in: pooled never leaves LDS; Wf1 read per-block is L2-resident, MLP'd
// (512 thr x 224 independent float2 loads, unroll 8) -- the round-2 k_head was a 90us
// zero-MLP latency chain (VALUBusy 0.5%).
// Edge loops: unroll-4, dual accumulators -> 8 independent ds_reads in flight.
// LDS strides: ds_read_b128 needs 16B-aligned rows: GSP=72 (144B), XP=136 (272B).
#define GSP 72                  // staging row stride in bf16
#define HP  132                 // h row stride in f32 (scalar access only)
#define XP  136                 // x1 row stride in bf16
__global__ __launch_bounds__(512) void k_gnn_fused(
        const ushort* __restrict__ nfb, const ushort* __restrict__ W1T,
        const ushort* __restrict__ W2T,
        const int* __restrict__ rowptrG, const int* __restrict__ srcsG,
        const float* __restrict__ wnG, const float* __restrict__ dinvG,
        const float* __restrict__ b1, const float* __restrict__ b2,
        const float* __restrict__ lh,
        const float* __restrict__ Wf1, const float* __restrict__ bf1,
        const float* __restrict__ Wf2, const float* __restrict__ bf2,
        float* __restrict__ outG) {
    __shared__ __align__(16) ushort As[128 * GSP];   // 18.4KB  A-staging; reused as head in[896]
    __shared__ __align__(16) ushort Bs[128 * GSP];   // 18.4KB  B-staging; reused as head redW/hvec
    __shared__ __align__(16) float  hL[128 * HP];    // 67.6KB  GEMM out (pre-aggregation), f32
    __shared__ __align__(16) ushort xb[128 * XP];    // 34.8KB  x1 bf16 [d][k]
    __shared__ int   rp[Nz + 1];
    __shared__ int   srcl[Ez];
    __shared__ float wnl[Ez];
    __shared__ float dil[Nz];
    __shared__ float wsum[8 * 128];

    int b = blockIdx.x;
    int t = threadIdx.x;
    int w = t >> 6, lane = t & 63;
    int q = lane >> 4, l16 = lane & 15;
    int wm = w >> 2, wn2 = w & 3;                    // wave tile: rows wm*64+, cols wn2*32+

    // ---- CSR -> LDS ----
    if (t < Nz + 1) rp[t] = rowptrG[b * (Nz + 1) + t];
    if (t < Nz) dil[t] = dinvG[b * Nz + t];
    #pragma unroll
    for (int j = 0; j < 2; ++j) {
        int e = t + 512 * j;
        srcl[e] = srcsG[b * Ez + e];
        wnl[e]  = wnG[b * Ez + e];
    }

    // staging decomposition: 1024 uint4 chunks (128 rows x 8 k-segs), 2 per thread
    int r0 = t >> 3, s0 = t & 7;                     // r0 in 0..63
    int r1 = r0 + 64;

    f32x4 acc[4][2];
    #pragma unroll
    for (int mf = 0; mf < 4; ++mf)
        #pragma unroll
        for (int nf = 0; nf < 2; ++nf) acc[mf][nf] = (f32x4){0, 0, 0, 0};

    // ---- GEMM1: hL = nf(128x768) @ W1(768x128), reg-prefetched 64-k steps ----
    const ushort* Ab = nfb + (size_t)b * Nz * Hz;
    uint4 apre[2], bpre[2];
    auto loadT1 = [&](int k0) {
        apre[0] = *(const uint4*)&Ab[(size_t)r0 * Hz + k0 + s0 * 8];
        apre[1] = *(const uint4*)&Ab[(size_t)r1 * Hz + k0 + s0 * 8];
        bpre[0] = *(const uint4*)&W1T[(size_t)r0 * Hz + k0 + s0 * 8];
        bpre[1] = *(const uint4*)&W1T[(size_t)r1 * Hz + k0 + s0 * 8];
    };
    loadT1(0);
    for (int k0 = 0; k0 < Hz; k0 += 64) {
        __syncthreads();
        *(uint4*)&As[r0 * GSP + s0 * 8] = apre[0];
        *(uint4*)&As[r1 * GSP + s0 * 8] = apre[1];
        *(uint4*)&Bs[r0 * GSP + s0 * 8] = bpre[0];
        *(uint4*)&Bs[r1 * GSP + s0 * 8] = bpre[1];
        if (k0 + 64 < Hz) loadT1(k0 + 64);
        __syncthreads();
        #pragma unroll
        for (int ks = 0; ks < 64; ks += 32)
            #pragma unroll
            for (int mf = 0; mf < 4; ++mf) {
                bf16x8 af = *(const bf16x8*)&As[(wm * 64 + mf * 16 + l16) * GSP + ks + q * 8];
                #pragma unroll
                for (int nf = 0; nf < 2; ++nf) {
                    bf16x8 bv = *(const bf16x8*)&Bs[(wn2 * 32 + nf * 16 + l16) * GSP + ks + q * 8];
                    acc[mf][nf] = __builtin_amdgcn_mfma_f32_16x16x32_bf16(af, bv, acc[mf][nf], 0, 0, 0);
                }
            }
    }
    #pragma unroll
    for (int mf = 0; mf < 4; ++mf)
        #pragma unroll
        for (int nf = 0; nf < 2; ++nf)
            #pragma unroll
            for (int r = 0; r < 4; ++r)
                hL[(wm * 64 + mf * 16 + q * 4 + r) * HP + wn2 * 32 + nf * 16 + l16] = acc[mf][nf][r];
    __syncthreads();

    // head input buffer (As region is free after GEMM1) -- issue cls loads now, they
    // overlap with edge1/GEMM2/edge2.
    float* inL = (float*)As;                 // [896]
    if (t < 256) {
        inL[t]       = lh[(size_t)b * Sz * Hz + t];
        inL[t + 256] = lh[(size_t)b * Sz * Hz + t + 256];
        inL[t + 512] = lh[(size_t)b * Sz * Hz + t + 512];
    }

    // ---- edge1: x1 = relu(agg(hL) + b1) -> xb bf16 (unroll-4, dual acc for MLP) ----
    float b1v0 = b1[lane], b1v1 = b1[lane + 64];
    for (int d = w; d < Nz; d += 8) {
        float dd = dil[d];
        float a0 = hL[d * HP + lane] * dd * dd;
        float a1 = hL[d * HP + lane + 64] * dd * dd;
        float c0 = 0.f, c1 = 0.f;
        int i = rp[d], pe = rp[d + 1];
        for (; i + 4 <= pe; i += 4) {
            int s0_ = srcl[i], s1_ = srcl[i+1], s2_ = srcl[i+2], s3_ = srcl[i+3];
            float n0 = wnl[i], n1 = wnl[i+1], n2 = wnl[i+2], n3 = wnl[i+3];
            float h0a = hL[s0_*HP+lane], h0b = hL[s0_*HP+lane+64];
            float h1a = hL[s1_*HP+lane], h1b = hL[s1_*HP+lane+64];
            float h2a = hL[s2_*HP+lane], h2b = hL[s2_*HP+lane+64];
            float h3a = hL[s3_*HP+lane], h3b = hL[s3_*HP+lane+64];
            a0 += h0a*n0; a1 += h0b*n0; c0 += h1a*n1; c1 += h1b*n1;
            a0 += h2a*n2; a1 += h2b*n2; c0 += h3a*n3; c1 += h3b*n3;
        }
        for (; i < pe; ++i) {
            int s_ = srcl[i]; float nm = wnl[i];
            a0 += hL[s_*HP+lane]*nm; a1 += hL[s_*HP+lane+64]*nm;
        }
        a0 += c0; a1 += c1;
        xb[d * XP + lane]      = f2b(fmaxf(a0 + b1v0, 0.0f));
        xb[d * XP + lane + 64] = f2b(fmaxf(a1 + b1v1, 0.0f));
    }
    __syncthreads();

    // ---- GEMM2: hL = x1(128x128, LDS) @ W2(128x128) ----
    #pragma unroll
    for (int mf = 0; mf < 4; ++mf)
        #pragma unroll
        for (int nf = 0; nf < 2; ++nf) acc[mf][nf] = (f32x4){0, 0, 0, 0};
    for (int k0 = 0; k0 < GHz; k0 += 64) {
        __syncthreads();
        *(uint4*)&Bs[r0 * GSP + s0 * 8] = *(const uint4*)&W2T[(size_t)r0 * GHz + k0 + s0 * 8];
        *(uint4*)&Bs[r1 * GSP + s0 * 8] = *(const uint4*)&W2T[(size_t)r1 * GHz + k0 + s0 * 8];
        __syncthreads();
        #pragma unroll
        for (int ks = 0; ks < 64; ks += 32)
            #pragma unroll
            for (int mf = 0; mf < 4; ++mf) {
                bf16x8 af = *(const bf16x8*)&xb[(wm * 64 + mf * 16 + l16) * XP + k0 + ks + q * 8];
                #pragma unroll
                for (int nf = 0; nf < 2; ++nf) {
                    bf16x8 bv = *(const bf16x8*)&Bs[(wn2 * 32 + nf * 16 + l16) * GSP + ks + q * 8];
                    acc[mf][nf] = __builtin_amdgcn_mfma_f32_16x16x32_bf16(af, bv, acc[mf][nf], 0, 0, 0);
                }
            }
    }
    #pragma unroll
    for (int mf = 0; mf < 4; ++mf)
        #pragma unroll
        for (int nf = 0; nf < 2; ++nf)
            #pragma unroll
            for (int r = 0; r < 4; ++r)
                hL[(wm * 64 + mf * 16 + q * 4 + r) * HP + wn2 * 32 + nf * 16 + l16] = acc[mf][nf][r];
    __syncthreads();

    // ---- edge2 + mean-pool (x2 never materialized) ----
    float b2v0 = b2[lane], b2v1 = b2[lane + 64];
    float p0 = 0.0f, p1 = 0.0f;
    for (int d = w; d < Nz; d += 8) {
        float dd = dil[d];
        float a0 = hL[d * HP + lane] * dd * dd;
        float a1 = hL[d * HP + lane + 64] * dd * dd;
        float c0 = 0.f, c1 = 0.f;
        int i = rp[d], pe = rp[d + 1];
        for (; i + 4 <= pe; i += 4) {
            int s0_ = srcl[i], s1_ = srcl[i+1], s2_ = srcl[i+2], s3_ = srcl[i+3];
            float n0 = wnl[i], n1 = wnl[i+1], n2 = wnl[i+2], n3 = wnl[i+3];
            float h0a = hL[s0_*HP+lane], h0b = hL[s0_*HP+lane+64];
            float h1a = hL[s1_*HP+lane], h1b = hL[s1_*HP+lane+64];
            float h2a = hL[s2_*HP+lane], h2b = hL[s2_*HP+lane+64];
            float h3a = hL[s3_*HP+lane], h3b = hL[s3_*HP+lane+64];
            a0 += h0a*n0; a1 += h0b*n0; c0 += h1a*n1; c1 += h1b*n1;
            a0 += h2a*n2; a1 += h2b*n2; c0 += h3a*n3; c1 += h3b*n3;
        }
        for (; i < pe; ++i) {
            int s_ = srcl[i]; float nm = wnl[i];
            a0 += hL[s_*HP+lane]*nm; a1 += hL[s_*HP+lane+64]*nm;
        }
        a0 += c0; a1 += c1;
        p0 += fmaxf(a0 + b2v0, 0.0f);
        p1 += fmaxf(a1 + b2v1, 0.0f);
    }
    wsum[w * 128 + lane]      = p0;
    wsum[w * 128 + lane + 64] = p1;
    __syncthreads();
    if (t < Nz) {
        float s = 0.0f;
        #pragma unroll
        for (int ww = 0; ww < 8; ++ww) s += wsum[ww * 128 + t];
        inL[Hz + t] = s * (1.0f / Nz);          // pooled -> head input
    }
    __syncthreads();

    // ---- head: out[b] = relu(in@Wf1+bf1) @ Wf2 + bf2 ----
    // 512 thr: f2 = t&127 (float2 column pair), kc4 = t>>7 (4-way k split, 224 each).
    // 224 independent float2 loads/thread, unroll 8 -> deep MLP on L2-resident Wf1.
    float* redW  = (float*)Bs;                   // [4][256]
    float* hvecL = ((float*)Bs) + 1024;          // [256]
    {
        int f2 = t & 127, kc4 = t >> 7;
        const float* Wp = Wf1 + (size_t)(kc4 * 224) * FHz + f2 * 2;
        const float* ip = inL + kc4 * 224;
        float ax = 0.f, ay = 0.f;
        #pragma unroll 8
        for (int k = 0; k < 224; ++k) {
            float iv = ip[k];
            float2 wv = *(const float2*)&Wp[(size_t)k * FHz];
            ax += iv * wv.x; ay += iv * wv.y;
        }
        redW[kc4 * 256 + f2 * 2]     = ax;
        redW[kc4 * 256 + f2 * 2 + 1] = ay;
    }
    __syncthreads();
    if (t < 128) {
        float2 s0 = *(const float2*)&redW[t*2],       s1 = *(const float2*)&redW[256 + t*2];
        float2 s2 = *(const float2*)&redW[512 + t*2], s3 = *(const float2*)&redW[768 + t*2];
        float2 bb = *(const float2*)&bf1[t*2];
        hvecL[t*2]     = fmaxf(s0.x + s1.x + s2.x + s3.x + bb.x, 0.0f);
        hvecL[t*2 + 1] = fmaxf(s0.y + s1.y + s2.y + s3.y + bb.y, 0.0f);
    }
    __syncthreads();
    if (t < 128) {
        int l = t >> 6, j0 = t & 63;
        float s = 0.0f;
        #pragma unroll
        for (int m = 0; m < 4; ++m) s += hvecL[j0 + 64*m] * Wf2[(j0 + 64*m) * Lz + l];
        #pragma unroll
        for (int off = 32; off > 0; off >>= 1) s += __shfl_down(s, off);
        if (j0 == 0) outG[b * Lz + l] = s + bf2[l];
    }
}

extern "C" void kernel_launch(void* const* d_in, const int* in_sizes, int n_in,
                              void* d_out, int out_size, void* d_ws, size_t ws_size,
                              hipStream_t stream) {
    const float* lh     = (const float*)d_in[0];
    const int*   submap = (const int*)d_in[1];
    const int*   ei     = (const int*)d_in[2];
    const float* wr  = (const float*)d_in[4];
    const float* br  = (const float*)d_in[5];
    const float* W1  = (const float*)d_in[6];
    const float* b1  = (const float*)d_in[7];
    const float* W2  = (const float*)d_in[8];
    const float* b2  = (const float*)d_in[9];
    const float* Wf1 = (const float*)d_in[10];
    const float* bf1 = (const float*)d_in[11];
    const float* Wf2 = (const float*)d_in[12];
    const float* bf2 = (const float*)d_in[13];
    float* out = (float*)d_out;

    // ---- workspace layout (16B-aligned chunks) ----
    char* p = (char*)d_ws;
    ushort* nfb  = (ushort*)p;  p += (size_t)BNz * Hz * 2;      // 12.6 MB bf16
    ushort* W1T  = (ushort*)p;  p += (size_t)Hz * GHz * 2;      // transposed [n][k]
    ushort* W2T  = (ushort*)p;  p += (size_t)GHz * GHz * 2;     // transposed [n][k]
    int*    rowptrG = (int*)p;  p += (size_t)Bz * (Nz + 1) * 4;
    int*    srcsG   = (int*)p;  p += (size_t)Bz * Ez * 4;
    float*  wnG     = (float*)p; p += (size_t)Bz * Ez * 4;
    float*  dinvG   = (float*)p; p += (size_t)Bz * Nz * 4;

    // 3 dispatches; no memsets, no global atomics; GNN+head intermediates never leave LDS
    k_prep<<<512, 256, 0, stream>>>(W1, W2, ei, W1T, W2T, rowptrG, srcsG, wnG, dinvG);
    k_node_gather<<<dim3(Nz, Bz), 128, 0, stream>>>(lh, submap, wr, br, nfb);
    k_gnn_fused<<<Bz, 512, 0, stream>>>(nfb, W1T, W2T, rowptrG, srcsG, wnG, dinvG,
                                        b1, b2, lh, Wf1, bf1, Wf2, bf2, out);
}

// Round 4
// 213.919 us; speedup vs baseline: 1.5188x; 1.1594x over previous
//
#include <hip/hip_runtime.h>
#include <math.h>

#define Bz 64
#define Sz 512
#define Hz 768
#define Nz 128
#define Ez 1024
#define GHz 128
#define FHz 256
#define Lz 2
#define BNz (Bz * Nz)          // 8192

typedef short bf16x8 __attribute__((ext_vector_type(8)));
typedef float f32x4  __attribute__((ext_vector_type(4)));
typedef unsigned short ushort;

__device__ inline ushort f2b(float f) {          // f32 -> bf16 bits, round-to-nearest-even
    union { float f; unsigned u; } v; v.f = f;
    return (ushort)((v.u + 0x7FFFu + ((v.u >> 16) & 1u)) >> 16);
}

// ============ k_stage: node gather (blocks 0..8191) + weight transpose (8192..8959)
//              + per-batch CSR build (8960..9023).  Merges old k_prep (one less dispatch);
//              CSR prefix scan is now a wave shuffle-scan (old serial t==0 loop ~6us).
__global__ __launch_bounds__(128) void k_stage(
        const float* __restrict__ lh, const int* __restrict__ submap,
        const float* __restrict__ wr, const float* __restrict__ br,
        const float* __restrict__ W1, const float* __restrict__ W2,
        const int* __restrict__ ei,
        ushort* __restrict__ nfb, ushort* __restrict__ W1T, ushort* __restrict__ W2T,
        int* __restrict__ rowptrG, int* __restrict__ srcsG,
        float* __restrict__ wnG, float* __restrict__ dinvG) {
    int blk = blockIdx.x, t = threadIdx.x;       // 128 threads
    __shared__ int list[Sz];
    __shared__ int lcnt;
    __shared__ float partial[Hz];
    __shared__ int srcl2[Ez], dstl2[Ez];
    __shared__ int hist[Nz], off[Nz], rp[Nz + 1];
    __shared__ float di[Nz];

    if (blk >= 8192 && blk < 8960) {             // ---- weight conversion + transpose ----
        int i = (blk - 8192) * 128 + t;          // 0..98303 == Hz*GHz
        { int k = i >> 7, n = i & 127; W1T[n * Hz + k] = f2b(W1[i]); }
        if (i < GHz * GHz) { int k = i >> 7, n = i & 127; W2T[n * GHz + k] = f2b(W2[i]); }
        return;
    }
    if (blk >= 8960) {                           // ---- CSR build, 1 block per batch ----
        int b = blk - 8960;
        if (t < Nz) { hist[t] = 0; off[t] = 0; }
        __syncthreads();
        #pragma unroll
        for (int j = 0; j < 8; ++j) {
            int e = t + 128 * j;
            int s = ei[b * 2 * Ez + e], d = ei[b * 2 * Ez + Ez + e];
            srcl2[e] = s; dstl2[e] = d;
            atomicAdd(&hist[d], 1);
        }
        __syncthreads();
        if (t < Nz) {
            di[t] = rsqrtf((float)hist[t] + 1.0f);
            dinvG[b * Nz + t] = di[t];
        }
        __syncthreads();
        if (t < 64) {                            // wave shuffle-scan over 128 buckets
            int s0 = hist[2 * t], s1 = hist[2 * t + 1];
            int tot = s0 + s1, run = tot;
            #pragma unroll
            for (int o = 1; o < 64; o <<= 1) {
                int v = __shfl_up(run, o);
                if (t >= o) run += v;
            }
            int excl = run - tot;
            rp[2 * t] = excl; rp[2 * t + 1] = excl + s0;
            if (t == 63) rp[Nz] = run;
        }
        __syncthreads();
        #pragma unroll
        for (int j = 0; j < 8; ++j) {
            int e = t + 128 * j;
            int s = srcl2[e], d = dstl2[e];
            int pos = rp[d] + atomicAdd(&off[d], 1);
            srcsG[b * Ez + pos] = s;
            wnG[b * Ez + pos] = di[s] * di[d];
        }
        if (t < Nz) rowptrG[b * (Nz + 1) + t] = rp[t];
        if (t == 0) rowptrG[b * (Nz + 1) + Nz] = rp[Nz];
        return;
    }

    // ---- node gather: block = (b,n); wave-synchronous gate; writes nf in bf16 ----
    int b = blk >> 7, n = blk & 127;
    int lane = t & 63, wid = t >> 6;             // 2 waves
    if (t == 0) lcnt = 0;
    __syncthreads();
    #pragma unroll
    for (int j = 0; j < 4; ++j) {
        int s = t + 128 * j;
        if (submap[b * Sz + s] == n) { int p = atomicAdd(&lcnt, 1); list[p] = s; }
    }
    __syncthreads();
    int cnt = lcnt;
    float brv = br[0];
    const float* wp = wr + lane * 12;
    float4 w0 = *(const float4*)&wp[0];
    float4 w1 = *(const float4*)&wp[4];
    float4 w2 = *(const float4*)&wp[8];
    float4 a0 = {0,0,0,0}, a1 = {0,0,0,0}, a2 = {0,0,0,0};
    for (int i = wid; i < cnt; i += 2) {
        const float* x = lh + (size_t)(b * Sz + list[i]) * Hz + lane * 12;
        float4 v0 = *(const float4*)&x[0];
        float4 v1 = *(const float4*)&x[4];
        float4 v2 = *(const float4*)&x[8];
        float p = v0.x*w0.x + v0.y*w0.y + v0.z*w0.z + v0.w*w0.w
                + v1.x*w1.x + v1.y*w1.y + v1.z*w1.z + v1.w*w1.w
                + v2.x*w2.x + v2.y*w2.y + v2.z*w2.z + v2.w*w2.w;
        #pragma unroll
        for (int o = 32; o > 0; o >>= 1) p += __shfl_down(p, o);
        float z = __shfl(p, 0) + brv;
        float g = 1.0f / (1.0f + __expf(-z));
        a0.x += g*v0.x; a0.y += g*v0.y; a0.z += g*v0.z; a0.w += g*v0.w;
        a1.x += g*v1.x; a1.y += g*v1.y; a1.z += g*v1.z; a1.w += g*v1.w;
        a2.x += g*v2.x; a2.y += g*v2.y; a2.z += g*v2.z; a2.w += g*v2.w;
    }
    if (wid == 1) {
        float* pp = partial + lane * 12;
        *(float4*)&pp[0] = a0; *(float4*)&pp[4] = a1; *(float4*)&pp[8] = a2;
    }
    __syncthreads();
    if (wid == 0) {
        float invc = 1.0f / fmaxf((float)cnt, 1.0f);
        const float* pp = partial + lane * 12;
        float4 p0 = *(const float4*)&pp[0];
        float4 p1 = *(const float4*)&pp[4];
        float4 p2 = *(const float4*)&pp[8];
        float o[12];
        o[0]=(a0.x+p0.x)*invc; o[1]=(a0.y+p0.y)*invc; o[2]=(a0.z+p0.z)*invc; o[3]=(a0.w+p0.w)*invc;
        o[4]=(a1.x+p1.x)*invc; o[5]=(a1.y+p1.y)*invc; o[6]=(a1.z+p1.z)*invc; o[7]=(a1.w+p1.w)*invc;
        o[8]=(a2.x+p2.x)*invc; o[9]=(a2.y+p2.y)*invc; o[10]=(a2.z+p2.z)*invc; o[11]=(a2.w+p2.w)*invc;
        unsigned* ob = (unsigned*)(nfb + (size_t)(b * Nz + n) * Hz + lane * 12);
        #pragma unroll
        for (int j = 0; j < 6; ++j)
            ob[j] = (unsigned)f2b(o[2*j]) | ((unsigned)f2b(o[2*j+1]) << 16);
    }
}

// ============ fused per-batch GNN + HEAD, 1024 threads = 16 waves (4x4 wave grid) ============
// Round-3 measured: 69us with MfmaUtil 1%, VALUBusy 3.5% -> pure latency, 2 waves/SIMD.
// Fixes: 16 waves (4/SIMD); edge1 (waves 0-7) runs CONCURRENTLY with head cls@Wf1[0:768]
// (waves 8-15); all per-thread phase work halved.
// LDS strides: ds_read_b128 needs 16B-aligned rows: GSP=72 (144B), XP=136 (272B).
#define GSP 72                  // staging row stride in bf16
#define HP  132                 // h row stride in f32 (scalar access only)
#define XP  136                 // x1 row stride in bf16
__global__ __launch_bounds__(1024) void k_gnn_fused(
        const ushort* __restrict__ nfb, const ushort* __restrict__ W1T,
        const ushort* __restrict__ W2T,
        const int* __restrict__ rowptrG, const int* __restrict__ srcsG,
        const float* __restrict__ wnG, const float* __restrict__ dinvG,
        const float* __restrict__ b1, const float* __restrict__ b2,
        const float* __restrict__ lh,
        const float* __restrict__ Wf1, const float* __restrict__ bf1,
        const float* __restrict__ Wf2, const float* __restrict__ bf2,
        float* __restrict__ outG) {
    __shared__ __align__(16) ushort As[128 * GSP];   // 18.4KB; reused: head in[896]+redA[1024]
    __shared__ __align__(16) ushort Bs[128 * GSP];   // 18.4KB; reused: redB[2048]+hvec[256]
    __shared__ __align__(16) float  hL[128 * HP];    // 67.6KB  GEMM out (pre-aggregation)
    __shared__ __align__(16) ushort xb[128 * XP];    // 34.8KB  x1 bf16 [d][k]
    __shared__ int   rp[Nz + 1];
    __shared__ int   srcl[Ez];
    __shared__ float wnl[Ez];
    __shared__ float dil[Nz];
    __shared__ float wsum[16 * 128];                 // 8KB

    int b = blockIdx.x;
    int t = threadIdx.x;
    int w = t >> 6, lane = t & 63;
    int q = lane >> 4, l16 = lane & 15;
    int wm = w >> 2, wn2 = w & 3;                    // wave tile: rows wm*32+, cols wn2*32+

    // ---- CSR -> LDS (1 elem/thread) ----
    if (t < Nz + 1) rp[t] = rowptrG[b * (Nz + 1) + t];
    if (t < Nz) dil[t] = dinvG[b * Nz + t];
    srcl[t] = srcsG[b * Ez + t];
    wnl[t]  = wnG[b * Ez + t];

    // staging: 1024 uint4 chunks each for A and B (128 rows x 8 segs), 1 per thread
    int ar = t >> 3, as_ = t & 7;

    f32x4 acc[2][2];
    #pragma unroll
    for (int mf = 0; mf < 2; ++mf)
        #pragma unroll
        for (int nf = 0; nf < 2; ++nf) acc[mf][nf] = (f32x4){0, 0, 0, 0};

    // ---- GEMM1: hL = nf(128x768) @ W1(768x128), reg-prefetched 64-k steps ----
    const ushort* Ab = nfb + (size_t)b * Nz * Hz;
    uint4 apre, bpre;
    auto loadT1 = [&](int k0) {
        apre = *(const uint4*)&Ab[(size_t)ar * Hz + k0 + as_ * 8];
        bpre = *(const uint4*)&W1T[(size_t)ar * Hz + k0 + as_ * 8];
    };
    loadT1(0);
    for (int k0 = 0; k0 < Hz; k0 += 64) {
        __syncthreads();
        *(uint4*)&As[ar * GSP + as_ * 8] = apre;
        *(uint4*)&Bs[ar * GSP + as_ * 8] = bpre;
        if (k0 + 64 < Hz) loadT1(k0 + 64);
        __syncthreads();
        #pragma unroll
        for (int ks = 0; ks < 64; ks += 32)
            #pragma unroll
            for (int mf = 0; mf < 2; ++mf) {
                bf16x8 af = *(const bf16x8*)&As[(wm * 32 + mf * 16 + l16) * GSP + ks + q * 8];
                #pragma unroll
                for (int nf = 0; nf < 2; ++nf) {
                    bf16x8 bv = *(const bf16x8*)&Bs[(wn2 * 32 + nf * 16 + l16) * GSP + ks + q * 8];
                    acc[mf][nf] = __builtin_amdgcn_mfma_f32_16x16x32_bf16(af, bv, acc[mf][nf], 0, 0, 0);
                }
            }
    }
    #pragma unroll
    for (int mf = 0; mf < 2; ++mf)
        #pragma unroll
        for (int nf = 0; nf < 2; ++nf)
            #pragma unroll
            for (int r = 0; r < 4; ++r)
                hL[(wm * 32 + mf * 16 + q * 4 + r) * HP + wn2 * 32 + nf * 16 + l16] = acc[mf][nf][r];
    __syncthreads();                                 // As free; hL complete

    // ---- cls -> inL (As region) ----
    float* inL  = (float*)As;                        // [896]
    float* redA = inL + 896;                         // [4][256] head partial (k 0..767)
    if (t < 224) ((float4*)inL)[t] = ((const float4*)(lh + (size_t)b * Sz * Hz))[t];
    __syncthreads();                                 // inL visible to headA waves

    // ---- edge1 (waves 0..7) || headA: cls @ Wf1[0:768] (waves 8..15) ----
    if (w < 8) {
        float b1v0 = b1[lane], b1v1 = b1[lane + 64];
        for (int d = w; d < Nz; d += 8) {
            float dd = dil[d];
            float a0 = hL[d * HP + lane] * dd * dd;
            float a1 = hL[d * HP + lane + 64] * dd * dd;
            float c0 = 0.f, c1 = 0.f;
            int i = rp[d], pe = rp[d + 1];
            for (; i + 4 <= pe; i += 4) {
                int s0_ = srcl[i], s1_ = srcl[i+1], s2_ = srcl[i+2], s3_ = srcl[i+3];
                float n0 = wnl[i], n1 = wnl[i+1], n2 = wnl[i+2], n3 = wnl[i+3];
                float h0a = hL[s0_*HP+lane], h0b = hL[s0_*HP+lane+64];
                float h1a = hL[s1_*HP+lane], h1b = hL[s1_*HP+lane+64];
                float h2a = hL[s2_*HP+lane], h2b = hL[s2_*HP+lane+64];
                float h3a = hL[s3_*HP+lane], h3b = hL[s3_*HP+lane+64];
                a0 += h0a*n0; a1 += h0b*n0; c0 += h1a*n1; c1 += h1b*n1;
                a0 += h2a*n2; a1 += h2b*n2; c0 += h3a*n3; c1 += h3b*n3;
            }
            for (; i < pe; ++i) {
                int s_ = srcl[i]; float nm = wnl[i];
                a0 += hL[s_*HP+lane]*nm; a1 += hL[s_*HP+lane+64]*nm;
            }
            a0 += c0; a1 += c1;
            xb[d * XP + lane]      = f2b(fmaxf(a0 + b1v0, 0.0f));
            xb[d * XP + lane + 64] = f2b(fmaxf(a1 + b1v1, 0.0f));
        }
    } else {
        int tt = t - 512;
        int f2 = tt & 127, kq = tt >> 7;             // 4-way k split, 192 each
        const float* Wp = Wf1 + (size_t)(kq * 192) * FHz + f2 * 2;
        const float* ip = inL + kq * 192;
        float ax = 0.f, ay = 0.f;
        #pragma unroll 8
        for (int k = 0; k < 192; ++k) {
            float iv = ip[k];
            float2 wv = *(const float2*)&Wp[(size_t)k * FHz];
            ax += iv * wv.x; ay += iv * wv.y;
        }
        redA[kq * 256 + f2 * 2]     = ax;
        redA[kq * 256 + f2 * 2 + 1] = ay;
    }
    __syncthreads();

    // ---- GEMM2: hL = x1(128x128, LDS) @ W2(128x128) ----
    #pragma unroll
    for (int mf = 0; mf < 2; ++mf)
        #pragma unroll
        for (int nf = 0; nf < 2; ++nf) acc[mf][nf] = (f32x4){0, 0, 0, 0};
    for (int k0 = 0; k0 < GHz; k0 += 64) {
        __syncthreads();
        *(uint4*)&Bs[ar * GSP + as_ * 8] = *(const uint4*)&W2T[(size_t)ar * GHz + k0 + as_ * 8];
        __syncthreads();
        #pragma unroll
        for (int ks = 0; ks < 64; ks += 32)
            #pragma unroll
            for (int mf = 0; mf < 2; ++mf) {
                bf16x8 af = *(const bf16x8*)&xb[(wm * 32 + mf * 16 + l16) * XP + k0 + ks + q * 8];
                #pragma unroll
                for (int nf = 0; nf < 2; ++nf) {
                    bf16x8 bv = *(const bf16x8*)&Bs[(wn2 * 32 + nf * 16 + l16) * GSP + ks + q * 8];
                    acc[mf][nf] = __builtin_amdgcn_mfma_f32_16x16x32_bf16(af, bv, acc[mf][nf], 0, 0, 0);
                }
            }
    }
    __syncthreads();                                 // xb/Bs readers done before hL rewrite is seen
    #pragma unroll
    for (int mf = 0; mf < 2; ++mf)
        #pragma unroll
        for (int nf = 0; nf < 2; ++nf)
            #pragma unroll
            for (int r = 0; r < 4; ++r)
                hL[(wm * 32 + mf * 16 + q * 4 + r) * HP + wn2 * 32 + nf * 16 + l16] = acc[mf][nf][r];
    __syncthreads();

    // ---- edge2 + mean-pool (all 16 waves, 8 d's each) ----
    float b2v0 = b2[lane], b2v1 = b2[lane + 64];
    float p0 = 0.0f, p1 = 0.0f;
    for (int d = w; d < Nz; d += 16) {
        float dd = dil[d];
        float a0 = hL[d * HP + lane] * dd * dd;
        float a1 = hL[d * HP + lane + 64] * dd * dd;
        float c0 = 0.f, c1 = 0.f;
        int i = rp[d], pe = rp[d + 1];
        for (; i + 4 <= pe; i += 4) {
            int s0_ = srcl[i], s1_ = srcl[i+1], s2_ = srcl[i+2], s3_ = srcl[i+3];
            float n0 = wnl[i], n1 = wnl[i+1], n2 = wnl[i+2], n3 = wnl[i+3];
            float h0a = hL[s0_*HP+lane], h0b = hL[s0_*HP+lane+64];
            float h1a = hL[s1_*HP+lane], h1b = hL[s1_*HP+lane+64];
            float h2a = hL[s2_*HP+lane], h2b = hL[s2_*HP+lane+64];
            float h3a = hL[s3_*HP+lane], h3b = hL[s3_*HP+lane+64];
            a0 += h0a*n0; a1 += h0b*n0; c0 += h1a*n1; c1 += h1b*n1;
            a0 += h2a*n2; a1 += h2b*n2; c0 += h3a*n3; c1 += h3b*n3;
        }
        for (; i < pe; ++i) {
            int s_ = srcl[i]; float nm = wnl[i];
            a0 += hL[s_*HP+lane]*nm; a1 += hL[s_*HP+lane+64]*nm;
        }
        a0 += c0; a1 += c1;
        p0 += fmaxf(a0 + b2v0, 0.0f);
        p1 += fmaxf(a1 + b2v1, 0.0f);
    }
    wsum[w * 128 + lane]      = p0;
    wsum[w * 128 + lane + 64] = p1;
    __syncthreads();
    if (t < Nz) {
        float s = 0.0f;
        #pragma unroll
        for (int ww = 0; ww < 16; ++ww) s += wsum[ww * 128 + t];
        inL[Hz + t] = s * (1.0f / Nz);               // pooled -> head input
    }
    __syncthreads();

    // ---- headB: pooled @ Wf1[768:896] (all threads, 16 k each) ----
    float* redB  = (float*)Bs;                       // [8][256]
    float* hvecL = ((float*)Bs) + 2048;              // [256]
    {
        int f2 = t & 127, kc8 = t >> 7;
        const float* Wp = Wf1 + (size_t)(Hz + kc8 * 16) * FHz + f2 * 2;
        const float* ip = inL + Hz + kc8 * 16;
        float ax = 0.f, ay = 0.f;
        #pragma unroll
        for (int k = 0; k < 16; ++k) {
            float iv = ip[k];
            float2 wv = *(const float2*)&Wp[(size_t)k * FHz];
            ax += iv * wv.x; ay += iv * wv.y;
        }
        redB[kc8 * 256 + f2 * 2]     = ax;
        redB[kc8 * 256 + f2 * 2 + 1] = ay;
    }
    __syncthreads();
    if (t < 128) {
        float sx = bf1[2 * t], sy = bf1[2 * t + 1];
        #pragma unroll
        for (int m = 0; m < 4; ++m) { sx += redA[m * 256 + 2 * t]; sy += redA[m * 256 + 2 * t + 1]; }
        #pragma unroll
        for (int m = 0; m < 8; ++m) { sx += redB[m * 256 + 2 * t]; sy += redB[m * 256 + 2 * t + 1]; }
        hvecL[2 * t]     = fmaxf(sx, 0.0f);
        hvecL[2 * t + 1] = fmaxf(sy, 0.0f);
    }
    __syncthreads();
    if (t < 128) {
        int l = t >> 6, j0 = t & 63;
        float s = 0.0f;
        #pragma unroll
        for (int m = 0; m < 4; ++m) s += hvecL[j0 + 64 * m] * Wf2[(j0 + 64 * m) * Lz + l];
        #pragma unroll
        for (int o = 32; o > 0; o >>= 1) s += __shfl_down(s, o);
        if (j0 == 0) outG[b * Lz + l] = s + bf2[l];
    }
}

extern "C" void kernel_launch(void* const* d_in, const int* in_sizes, int n_in,
                              void* d_out, int out_size, void* d_ws, size_t ws_size,
                              hipStream_t stream) {
    const float* lh     = (const float*)d_in[0];
    const int*   submap = (const int*)d_in[1];
    const int*   ei     = (const int*)d_in[2];
    const float* wr  = (const float*)d_in[4];
    const float* br  = (const float*)d_in[5];
    const float* W1  = (const float*)d_in[6];
    const float* b1  = (const float*)d_in[7];
    const float* W2  = (const float*)d_in[8];
    const float* b2  = (const float*)d_in[9];
    const float* Wf1 = (const float*)d_in[10];
    const float* bf1 = (const float*)d_in[11];
    const float* Wf2 = (const float*)d_in[12];
    const float* bf2 = (const float*)d_in[13];
    float* out = (float*)d_out;

    // ---- workspace layout (16B-aligned chunks) ----
    char* p = (char*)d_ws;
    ushort* nfb  = (ushort*)p;  p += (size_t)BNz * Hz * 2;      // 12.6 MB bf16
    ushort* W1T  = (ushort*)p;  p += (size_t)Hz * GHz * 2;      // transposed [n][k]
    ushort* W2T  = (ushort*)p;  p += (size_t)GHz * GHz * 2;     // transposed [n][k]
    int*    rowptrG = (int*)p;  p += (size_t)Bz * (Nz + 1) * 4;
    int*    srcsG   = (int*)p;  p += (size_t)Bz * Ez * 4;
    float*  wnG     = (float*)p; p += (size_t)Bz * Ez * 4;
    float*  dinvG   = (float*)p; p += (size_t)Bz * Nz * 4;

    // 2 dispatches; no memsets, no global atomics; GNN+head intermediates never leave LDS
    k_stage<<<8192 + 768 + 64, 128, 0, stream>>>(lh, submap, wr, br, W1, W2, ei,
                                                 nfb, W1T, W2T, rowptrG, srcsG, wnG, dinvG);
    k_gnn_fused<<<Bz, 1024, 0, stream>>>(nfb, W1T, W2T, rowptrG, srcsG, wnG, dinvG,
                                         b1, b2, lh, Wf1, bf1, Wf2, bf2, out);
}